// Round 18
// baseline (570.223 us; speedup 1.0000x reference)
//
#include <hip/hip_runtime.h>
#include <hip/hip_bf16.h>

#define NNODES 50000
#define NPAD   50048
#define NEDGES 800000
#define ETOT   (NEDGES + NNODES)
#define FIN    256
#define HIDS   32
#define HEADS  8
#define NCLS   40
#define NEG    0.2f

#define SCAN_B 256
#define NSCB   ((NNODES + SCAN_B - 1) / SCAN_B)   // 196
#define NTILE1 ((NNODES + 63) / 64)               // 782 node-tiles

typedef __attribute__((ext_vector_type(8))) short bf16x8;
typedef __attribute__((ext_vector_type(4))) float f32x4;

__device__ __forceinline__ ushort f2bf(float f) {
  unsigned u = __float_as_uint(f);
  unsigned r = (u + 0x7fffu + ((u >> 16) & 1u)) >> 16;   // RNE
  return (ushort)r;
}
__device__ __forceinline__ float bf2f(ushort u) {
  return __uint_as_float(((unsigned)u) << 16);
}
__device__ __forceinline__ float bflo(unsigned u) { return __uint_as_float(u << 16); }
__device__ __forceinline__ float bfhi(unsigned u) { return __uint_as_float(u & 0xffff0000u); }

// ---------------- prep: w1t[320][256], w2t[64][256], cnt=0, hb pad rows=0, dbin=0 -------
__global__ __launch_bounds__(256) void prep_k(
    const float* __restrict__ W1, const float* __restrict__ W2,
    const float* __restrict__ a1src, const float* __restrict__ a1dst,
    const float* __restrict__ a2src, const float* __restrict__ a2dst,
    ushort* __restrict__ w1t, ushort* __restrict__ w2t,
    int* __restrict__ cnt, ushort* __restrict__ hb, int* __restrict__ dbin) {
  int b = blockIdx.x, t = threadIdx.x;
  if (b < 256) {
    int k = b, n = t;
    w1t[(size_t)n * 256 + k] = f2bf(W1[(size_t)k * 256 + n]);
  } else if (b < 272) {
    int j = b - 256, k = t;
    const float* av = (j < 8) ? (a1src + j * 32) : (a1dst + (j - 8) * 32);
    int nb = (j < 8) ? j * 32 : (j - 8) * 32;
    float s = 0.f;
#pragma unroll
    for (int c = 0; c < 32; ++c) s += W1[(size_t)k * 256 + nb + c] * av[c];
    w1t[(size_t)(256 + j) * 256 + k] = f2bf(s);
  } else if (b < 320) {
    w1t[(size_t)b * 256 + t] = 0;     // rows 272..319 zero
  } else if (b < 384) {
    int n = b - 320, k = t;
    ushort v;
    if (n < NCLS) {
      v = f2bf(W2[(size_t)k * NCLS + n]);
    } else if (n == 40) {
      float s = 0.f;
#pragma unroll
      for (int c = 0; c < NCLS; ++c) s += W2[(size_t)k * NCLS + c] * a2src[c];
      v = f2bf(s);
    } else if (n == 41) {
      float s = 0.f;
#pragma unroll
      for (int c = 0; c < NCLS; ++c) s += W2[(size_t)k * NCLS + c] * a2dst[c];
      v = f2bf(s);
    } else {
      v = 0;
    }
    w2t[(size_t)n * 256 + k] = v;
  } else if (b < 580) {
    int i = (b - 384) * 256 + t;
    if (i < NNODES) cnt[i] = 0;
  } else if (b < 628) {
    int r = NNODES + (b - 580);
    hb[(size_t)r * 256 + t] = 0;
  } else {
    dbin[t] = 0;
  }
}

// ---------------- GEMM1: [xw1s(slice-major) | a1sx | a1dx (slice-major)] via MFMA --------
__global__ __launch_bounds__(256) void gemm1_mfma(
    const float* __restrict__ x, const ushort* __restrict__ w1t,
    ushort* __restrict__ xw1s, float* __restrict__ a1sx, float* __restrict__ a1dx) {
  __shared__ ushort As[64 * 40];
  __shared__ ushort Bs[320 * 40];
  const int tid = threadIdx.x;
  const int m0 = blockIdx.x * 64;
  const int w = tid >> 6, l = tid & 63, lr = l & 15, lq = l >> 4;
  f32x4 acc[4][5];
#pragma unroll
  for (int i = 0; i < 4; ++i)
#pragma unroll
    for (int j = 0; j < 5; ++j) acc[i][j] = (f32x4)0.f;

  for (int k0 = 0; k0 < 256; k0 += 32) {
    {
      int row = tid >> 2, kg = (tid & 3) * 8;
      int gr = m0 + row;
      bf16x8 av;
      if (gr < NNODES) {
        const float4* xp = (const float4*)(x + (size_t)gr * 256 + k0 + kg);
        float4 p0 = xp[0], p1 = xp[1];
        av[0] = (short)f2bf(p0.x); av[1] = (short)f2bf(p0.y);
        av[2] = (short)f2bf(p0.z); av[3] = (short)f2bf(p0.w);
        av[4] = (short)f2bf(p1.x); av[5] = (short)f2bf(p1.y);
        av[6] = (short)f2bf(p1.z); av[7] = (short)f2bf(p1.w);
      } else {
        av = (bf16x8)0;
      }
      *(bf16x8*)&As[row * 40 + kg] = av;
    }
#pragma unroll
    for (int p = 0; p < 5; ++p) {
      int idx = tid + p * 256;
      int n = idx >> 2, kg = (idx & 3) * 8;
      *(bf16x8*)&Bs[n * 40 + kg] = *(const bf16x8*)(w1t + (size_t)n * 256 + k0 + kg);
    }
    __syncthreads();
    bf16x8 af[4], bfr[5];
#pragma unroll
    for (int mt = 0; mt < 4; ++mt)
      af[mt] = *(const bf16x8*)&As[(mt * 16 + lr) * 40 + lq * 8];
#pragma unroll
    for (int nt = 0; nt < 5; ++nt) {
      int tile = nt * 4 + w;
      bfr[nt] = *(const bf16x8*)&Bs[(tile * 16 + lr) * 40 + lq * 8];
    }
#pragma unroll
    for (int mt = 0; mt < 4; ++mt)
#pragma unroll
      for (int nt = 0; nt < 5; ++nt)
        acc[mt][nt] = __builtin_amdgcn_mfma_f32_16x16x32_bf16(af[mt], bfr[nt], acc[mt][nt], 0, 0, 0);
    __syncthreads();
  }
#pragma unroll
  for (int mt = 0; mt < 4; ++mt)
#pragma unroll
    for (int nt = 0; nt < 5; ++nt) {
      int tile = nt * 4 + w;
      if (tile < 16) {
        int colc = tile * 16 + lr;
        int s = colc >> 5, c = colc & 31;
#pragma unroll
        for (int r = 0; r < 4; ++r) {
          int row = m0 + mt * 16 + lq * 4 + r;
          xw1s[((size_t)s * NPAD + row) * 32 + c] = f2bf(acc[mt][nt][r]);
        }
      } else if (tile == 16) {
#pragma unroll
        for (int r = 0; r < 4; ++r) {
          int row = m0 + mt * 16 + lq * 4 + r;
          if (lr < 8) a1sx[(size_t)lr * NPAD + row] = acc[mt][nt][r];
          else        a1dx[(size_t)(lr - 8) * NPAD + row] = acc[mt][nt][r];
        }
      }
    }
}

// ---------------- GEMM2: [xw2b | a2s | a2d] = hb @ w2t^T via MFMA, LDS-free -----------
__global__ __launch_bounds__(256) void gemm2_mfma(
    const ushort* __restrict__ hb, const ushort* __restrict__ w2t,
    ushort* __restrict__ xw2b, float* __restrict__ a2s, float* __restrict__ a2d) {
  const int tid = threadIdx.x;
  const int w = tid >> 6, l = tid & 63, lr = l & 15, lq = l >> 4;
  const int row0 = blockIdx.x * 64 + w * 16;
  f32x4 acc[3];
#pragma unroll
  for (int i = 0; i < 3; ++i) acc[i] = (f32x4)0.f;
#pragma unroll
  for (int ks = 0; ks < 8; ++ks) {
    int k0 = ks * 32;
    bf16x8 af = *(const bf16x8*)(hb + (size_t)(row0 + lr) * 256 + k0 + lq * 8);
#pragma unroll
    for (int nt = 0; nt < 3; ++nt) {
      bf16x8 bfr = *(const bf16x8*)(w2t + (size_t)(nt * 16 + lr) * 256 + k0 + lq * 8);
      acc[nt] = __builtin_amdgcn_mfma_f32_16x16x32_bf16(af, bfr, acc[nt], 0, 0, 0);
    }
  }
#pragma unroll
  for (int nt = 0; nt < 3; ++nt) {
    int colc = nt * 16 + lr;
#pragma unroll
    for (int r = 0; r < 4; ++r) {
      int row = row0 + lq * 4 + r;
      if (colc < NCLS)      xw2b[(size_t)row * 40 + colc] = f2bf(acc[nt][r]);
      else if (colc == 40)  a2s[row] = acc[nt][r];
      else if (colc == 41)  a2d[row] = acc[nt][r];
    }
  }
}

// ---------------- CSR build ----------------
__global__ __launch_bounds__(256) void hist_k(const int* __restrict__ dstA, int* __restrict__ cnt) {
  int e = blockIdx.x * 256 + threadIdx.x;
  if (e >= ETOT) return;
  int d = (e < NEDGES) ? dstA[e] : (e - NEDGES);
  atomicAdd(&cnt[d], 1);
}

// scan1 + degree histogram (bins capped at 255)
__global__ __launch_bounds__(SCAN_B) void scan1_k(const int* __restrict__ deg,
                                                  int* __restrict__ row_ptr,
                                                  int* __restrict__ bsum,
                                                  int* __restrict__ dbin) {
  __shared__ int sm[SCAN_B];
  int b = blockIdx.x, t = threadIdx.x;
  int idx = b * SCAN_B + t;
  int v = (idx < NNODES) ? deg[idx] : 0;
  if (idx < NNODES) atomicAdd(&dbin[(v < 255) ? v : 255], 1);
  sm[t] = v;
  __syncthreads();
#pragma unroll
  for (int off = 1; off < SCAN_B; off <<= 1) {
    int u = (t >= off) ? sm[t - off] : 0;
    __syncthreads();
    sm[t] += u;
    __syncthreads();
  }
  if (idx < NNODES) row_ptr[idx + 1] = sm[t];
  if (t == SCAN_B - 1) bsum[b] = sm[t];
}

// fused scan2+scan3
__global__ __launch_bounds__(SCAN_B) void scan23_k(const int* __restrict__ bsum,
                                                   int* __restrict__ row_ptr) {
  __shared__ int sm[SCAN_B];
  int b = blockIdx.x, t = threadIdx.x;
  sm[t] = (t < NSCB) ? bsum[t] : 0;
  __syncthreads();
#pragma unroll
  for (int off = 1; off < SCAN_B; off <<= 1) {
    int u = (t >= off) ? sm[t - off] : 0;
    __syncthreads();
    sm[t] += u;
    __syncthreads();
  }
  int offb = (b > 0) ? sm[b - 1] : 0;
  int idx = b * SCAN_B + t;
  if (idx < NNODES) row_ptr[idx + 1] += offb;
  if (b == 0 && t == 0) row_ptr[0] = 0;
}

// exclusive scan of 256 degree bins (in place)
__global__ __launch_bounds__(256) void binscan_k(int* __restrict__ dbin) {
  __shared__ int sm[256];
  int t = threadIdx.x;
  sm[t] = dbin[t];
  __syncthreads();
#pragma unroll
  for (int off = 1; off < 256; off <<= 1) {
    int u = (t >= off) ? sm[t - off] : 0;
    __syncthreads();
    sm[t] += u;
    __syncthreads();
  }
  dbin[t] = (t > 0) ? sm[t - 1] : 0;
}

// counting-sort scatter: perm[pos] = node, sorted by degree
__global__ __launch_bounds__(256) void perm_k(const int* __restrict__ row_ptr,
                                              int* __restrict__ dbin,
                                              int* __restrict__ perm) {
  int n = blockIdx.x * 256 + threadIdx.x;
  if (n >= NNODES) return;
  int deg = row_ptr[n + 1] - row_ptr[n];
  int bin = (deg < 255) ? deg : 255;
  int pos = atomicAdd(&dbin[bin], 1);
  perm[pos] = n;
}

// scatter via atomicSub: cnt holds degrees on entry, zeros on exit
__global__ __launch_bounds__(256) void scatter_k(const int* __restrict__ srcA, const int* __restrict__ dstA,
                                                 const int* __restrict__ row_ptr, int* __restrict__ cnt,
                                                 int* __restrict__ col) {
  int e = blockIdx.x * 256 + threadIdx.x;
  if (e >= ETOT) return;
  int s, d;
  if (e < NEDGES) { s = srcA[e]; d = dstA[e]; }
  else { s = d = e - NEDGES; }
  int old = atomicSub(&cnt[d], 1);
  col[row_ptr[d] + old - 1] = s;
}

// ---------------- layer-1 aggregate: lane owns (node, 8ch), XCD-sliced, degree-sorted ---
// block = (slice s = blockIdx&7 -> XCD, 64-slot tile = blockIdx>>3). node = perm[slot]
// so all 16 nodes in a wave have near-equal degree (minimal loop divergence).
__global__ __launch_bounds__(256) void agg1_k(
    const ushort* __restrict__ xw1s, const float* __restrict__ a1sx, const float* __restrict__ a1dx,
    const int* __restrict__ row_ptr, const int* __restrict__ col, const int* __restrict__ perm,
    const float* __restrict__ b1, ushort* __restrict__ hb) {
  const int b = blockIdx.x;
  const int s = b & 7;
  const int t = threadIdx.x;
  const int slot = (b >> 3) * 64 + (t >> 2);
  const int q = t & 3;                           // channel quad: 8 channels
  if (slot >= NNODES) return;
  const int node = perm[slot];
  const ushort* xs = xw1s + (size_t)s * NPAD * 32 + q * 8;
  const float* as = a1sx + (size_t)s * NPAD;
  const float ad = a1dx[(size_t)s * NPAD + node];
  int i = row_ptr[node];
  const int end = row_ptr[node + 1];
  float den = 0.f;
  float c0 = 0.f, c1 = 0.f, c2 = 0.f, c3 = 0.f, c4 = 0.f, c5 = 0.f, c6 = 0.f, c7 = 0.f;
  for (; i + 2 <= end; i += 2) {
    int s0 = col[i], s1 = col[i + 1];
    uint4 u0 = *(const uint4*)(xs + (size_t)s0 * 32);
    uint4 u1 = *(const uint4*)(xs + (size_t)s1 * 32);
    float e0 = as[s0] + ad;
    float e1 = as[s1] + ad;
    float w0 = __expf(fmaxf(e0, 0.f) + NEG * fminf(e0, 0.f));
    float w1 = __expf(fmaxf(e1, 0.f) + NEG * fminf(e1, 0.f));
    den += w0 + w1;
    c0 += w0 * bflo(u0.x) + w1 * bflo(u1.x);
    c1 += w0 * bfhi(u0.x) + w1 * bfhi(u1.x);
    c2 += w0 * bflo(u0.y) + w1 * bflo(u1.y);
    c3 += w0 * bfhi(u0.y) + w1 * bfhi(u1.y);
    c4 += w0 * bflo(u0.z) + w1 * bflo(u1.z);
    c5 += w0 * bfhi(u0.z) + w1 * bfhi(u1.z);
    c6 += w0 * bflo(u0.w) + w1 * bflo(u1.w);
    c7 += w0 * bfhi(u0.w) + w1 * bfhi(u1.w);
  }
  if (i < end) {
    int s0 = col[i];
    uint4 u0 = *(const uint4*)(xs + (size_t)s0 * 32);
    float e0 = as[s0] + ad;
    float w0 = __expf(fmaxf(e0, 0.f) + NEG * fminf(e0, 0.f));
    den += w0;
    c0 += w0 * bflo(u0.x); c1 += w0 * bfhi(u0.x);
    c2 += w0 * bflo(u0.y); c3 += w0 * bfhi(u0.y);
    c4 += w0 * bflo(u0.z); c5 += w0 * bfhi(u0.z);
    c6 += w0 * bflo(u0.w); c7 += w0 * bfhi(u0.w);
  }
  const float inv = 1.f / den;
  const float4 bv0 = *reinterpret_cast<const float4*>(b1 + s * 32 + q * 8);
  const float4 bv1 = *reinterpret_cast<const float4*>(b1 + s * 32 + q * 8 + 4);
  float o[8];
  o[0] = c0 * inv + bv0.x; o[1] = c1 * inv + bv0.y;
  o[2] = c2 * inv + bv0.z; o[3] = c3 * inv + bv0.w;
  o[4] = c4 * inv + bv1.x; o[5] = c5 * inv + bv1.y;
  o[6] = c6 * inv + bv1.z; o[7] = c7 * inv + bv1.w;
  uint4 pk;
  unsigned r[4];
#pragma unroll
  for (int p = 0; p < 4; ++p) {
    float a = o[2 * p],     va = (a > 0.f) ? a : expm1f(a);
    float c = o[2 * p + 1], vc = (c > 0.f) ? c : expm1f(c);
    r[p] = (unsigned)f2bf(va) | ((unsigned)f2bf(vc) << 16);
  }
  pk.x = r[0]; pk.y = r[1]; pk.z = r[2]; pk.w = r[3];
  *(uint4*)(hb + (size_t)node * 256 + s * 32 + q * 8) = pk;
}

// ---------------- layer-2 aggregate: 1 wave per node (bf16 gather, pitch 40) ----------
__global__ __launch_bounds__(256) void agg2_k(
    const ushort* __restrict__ xw2b, const float* __restrict__ a2s, const float* __restrict__ a2d,
    const int* __restrict__ row_ptr, const int* __restrict__ col,
    const float* __restrict__ b2, float* __restrict__ out, int n) {
  int wid = (blockIdx.x * 256 + threadIdx.x) >> 6;
  if (wid >= n) return;
  int lane = threadIdx.x & 63;
  int beg = row_ptr[wid], end = row_ptr[wid + 1];
  float ad = a2d[wid];
  float denom = 0.f, acc = 0.f;
  int i = beg;
  for (; i + 4 <= end; i += 4) {
    int s0 = col[i], s1 = col[i + 1], s2 = col[i + 2], s3 = col[i + 3];
    float e0 = a2s[s0] + ad;
    float e1 = a2s[s1] + ad;
    float e2 = a2s[s2] + ad;
    float e3 = a2s[s3] + ad;
    float w0 = __expf(fmaxf(e0, 0.f) + NEG * fminf(e0, 0.f));
    float w1 = __expf(fmaxf(e1, 0.f) + NEG * fminf(e1, 0.f));
    float w2 = __expf(fmaxf(e2, 0.f) + NEG * fminf(e2, 0.f));
    float w3 = __expf(fmaxf(e3, 0.f) + NEG * fminf(e3, 0.f));
    float x0 = 0.f, x1 = 0.f, x2 = 0.f, x3 = 0.f;
    if (lane < NCLS) {
      x0 = bf2f(xw2b[(size_t)s0 * 40 + lane]);
      x1 = bf2f(xw2b[(size_t)s1 * 40 + lane]);
      x2 = bf2f(xw2b[(size_t)s2 * 40 + lane]);
      x3 = bf2f(xw2b[(size_t)s3 * 40 + lane]);
    }
    denom += (w0 + w1) + (w2 + w3);
    acc += w0 * x0 + w1 * x1 + w2 * x2 + w3 * x3;
  }
  for (; i < end; ++i) {
    int s = col[i];
    float e = a2s[s] + ad;
    float w = __expf(fmaxf(e, 0.f) + NEG * fminf(e, 0.f));
    denom += w;
    if (lane < NCLS) acc += w * bf2f(xw2b[(size_t)s * 40 + lane]);
  }
  if (lane < NCLS) out[(size_t)wid * 40 + lane] = acc / denom + b2[lane];
}

extern "C" void kernel_launch(void* const* d_in, const int* in_sizes, int n_in,
                              void* d_out, int out_size, void* d_ws, size_t ws_size,
                              hipStream_t stream) {
  const float* x     = (const float*)d_in[0];
  const int*   ei    = (const int*)d_in[1];
  const float* W1    = (const float*)d_in[2];
  const float* a1src = (const float*)d_in[3];
  const float* a1dst = (const float*)d_in[4];
  const float* b1    = (const float*)d_in[5];
  const float* W2    = (const float*)d_in[6];
  const float* a2src = (const float*)d_in[7];
  const float* a2dst = (const float*)d_in[8];
  const float* b2    = (const float*)d_in[9];
  float* out = (float*)d_out;

  const int* srcA = ei;
  const int* dstA = ei + NEDGES;

  // workspace layout
  ushort* w1t  = (ushort*)d_ws;                     // [320][256]
  ushort* w2t  = w1t + (size_t)320 * 256;           // [64][256]
  ushort* xw1s = w2t + (size_t)64 * 256;            // [8][NPAD][32] slice-major
  ushort* hb   = xw1s + (size_t)NPAD * 256;         // [NPAD][256]
  ushort* xw2b = hb + (size_t)NPAD * 256;           // [NPAD][40]
  float* a1sx  = (float*)(xw2b + (size_t)NPAD * 40);// [8][NPAD]
  float* a1dx  = a1sx + (size_t)8 * NPAD;           // [8][NPAD]
  float* a2s   = a1dx + (size_t)8 * NPAD;           // NPAD
  float* a2d   = a2s + NPAD;                        // NPAD
  int* row_ptr = (int*)(a2d + NPAD);                // NNODES+1
  int* cnt     = row_ptr + (NNODES + 1);            // NNODES
  int* col     = cnt + NNODES;                      // ETOT
  int* bsum    = col + ETOT;                        // NSCB
  int* dbin    = bsum + NSCB;                       // 256
  int* perm    = dbin + 256;                        // NNODES

  prep_k<<<629, 256, 0, stream>>>(W1, W2, a1src, a1dst, a2src, a2dst, w1t, w2t, cnt, hb, dbin);

  gemm1_mfma<<<NPAD / 64, 256, 0, stream>>>(x, w1t, xw1s, a1sx, a1dx);

  hist_k<<<(ETOT + 255) / 256, 256, 0, stream>>>(dstA, cnt);
  scan1_k<<<NSCB, SCAN_B, 0, stream>>>(cnt, row_ptr, bsum, dbin);
  scan23_k<<<NSCB, SCAN_B, 0, stream>>>(bsum, row_ptr);
  binscan_k<<<1, 256, 0, stream>>>(dbin);
  perm_k<<<NSCB, 256, 0, stream>>>(row_ptr, dbin, perm);
  scatter_k<<<(ETOT + 255) / 256, 256, 0, stream>>>(srcA, dstA, row_ptr, cnt, col);

  agg1_k<<<NTILE1 * 8, 256, 0, stream>>>(xw1s, a1sx, a1dx, row_ptr, col, perm, b1, hb);

  gemm2_mfma<<<NPAD / 64, 256, 0, stream>>>(hb, w2t, xw2b, a2s, a2d);

  agg2_k<<<(NNODES + 3) / 4, 256, 0, stream>>>(xw2b, a2s, a2d, row_ptr, col, b2, out, NNODES);
}

// Round 19
// 283.793 us; speedup vs baseline: 2.0093x; 2.0093x over previous
//
#include <hip/hip_runtime.h>
#include <hip/hip_bf16.h>

#define NNODES 50000
#define NPAD   50048
#define NEDGES 800000
#define ETOT   (NEDGES + NNODES)
#define FIN    256
#define HIDS   32
#define HEADS  8
#define NCLS   40
#define NEG    0.2f

#define SCAN_B 256
#define NSCB   ((NNODES + SCAN_B - 1) / SCAN_B)   // 196
#define NTILE1 ((NNODES + 63) / 64)               // 782 node-tiles

typedef __attribute__((ext_vector_type(8))) short bf16x8;
typedef __attribute__((ext_vector_type(4))) float f32x4;

__device__ __forceinline__ ushort f2bf(float f) {
  unsigned u = __float_as_uint(f);
  unsigned r = (u + 0x7fffu + ((u >> 16) & 1u)) >> 16;   // RNE
  return (ushort)r;
}
__device__ __forceinline__ float bf2f(ushort u) {
  return __uint_as_float(((unsigned)u) << 16);
}
__device__ __forceinline__ float bflo(unsigned u) { return __uint_as_float(u << 16); }
__device__ __forceinline__ float bfhi(unsigned u) { return __uint_as_float(u & 0xffff0000u); }

// ---------------- prep: w1t[320][256], w2t[64][256], cnt=0, hb pad rows=0, dbin=0 -------
__global__ __launch_bounds__(256) void prep_k(
    const float* __restrict__ W1, const float* __restrict__ W2,
    const float* __restrict__ a1src, const float* __restrict__ a1dst,
    const float* __restrict__ a2src, const float* __restrict__ a2dst,
    ushort* __restrict__ w1t, ushort* __restrict__ w2t,
    int* __restrict__ cnt, ushort* __restrict__ hb, int* __restrict__ dbin) {
  int b = blockIdx.x, t = threadIdx.x;
  if (b < 256) {
    int k = b, n = t;
    w1t[(size_t)n * 256 + k] = f2bf(W1[(size_t)k * 256 + n]);
  } else if (b < 272) {
    int j = b - 256, k = t;
    const float* av = (j < 8) ? (a1src + j * 32) : (a1dst + (j - 8) * 32);
    int nb = (j < 8) ? j * 32 : (j - 8) * 32;
    float s = 0.f;
#pragma unroll
    for (int c = 0; c < 32; ++c) s += W1[(size_t)k * 256 + nb + c] * av[c];
    w1t[(size_t)(256 + j) * 256 + k] = f2bf(s);
  } else if (b < 320) {
    w1t[(size_t)b * 256 + t] = 0;     // rows 272..319 zero
  } else if (b < 384) {
    int n = b - 320, k = t;
    ushort v;
    if (n < NCLS) {
      v = f2bf(W2[(size_t)k * NCLS + n]);
    } else if (n == 40) {
      float s = 0.f;
#pragma unroll
      for (int c = 0; c < NCLS; ++c) s += W2[(size_t)k * NCLS + c] * a2src[c];
      v = f2bf(s);
    } else if (n == 41) {
      float s = 0.f;
#pragma unroll
      for (int c = 0; c < NCLS; ++c) s += W2[(size_t)k * NCLS + c] * a2dst[c];
      v = f2bf(s);
    } else {
      v = 0;
    }
    w2t[(size_t)n * 256 + k] = v;
  } else if (b < 580) {
    int i = (b - 384) * 256 + t;
    if (i < NNODES) cnt[i] = 0;
  } else if (b < 628) {
    int r = NNODES + (b - 580);
    hb[(size_t)r * 256 + t] = 0;
  } else {
    dbin[t] = 0;
  }
}

// ---------------- GEMM1: [xw1s(slice-major) | a1sx | a1dx (slice-major)] via MFMA --------
__global__ __launch_bounds__(256) void gemm1_mfma(
    const float* __restrict__ x, const ushort* __restrict__ w1t,
    ushort* __restrict__ xw1s, float* __restrict__ a1sx, float* __restrict__ a1dx) {
  __shared__ ushort As[64 * 40];
  __shared__ ushort Bs[320 * 40];
  const int tid = threadIdx.x;
  const int m0 = blockIdx.x * 64;
  const int w = tid >> 6, l = tid & 63, lr = l & 15, lq = l >> 4;
  f32x4 acc[4][5];
#pragma unroll
  for (int i = 0; i < 4; ++i)
#pragma unroll
    for (int j = 0; j < 5; ++j) acc[i][j] = (f32x4)0.f;

  for (int k0 = 0; k0 < 256; k0 += 32) {
    {
      int row = tid >> 2, kg = (tid & 3) * 8;
      int gr = m0 + row;
      bf16x8 av;
      if (gr < NNODES) {
        const float4* xp = (const float4*)(x + (size_t)gr * 256 + k0 + kg);
        float4 p0 = xp[0], p1 = xp[1];
        av[0] = (short)f2bf(p0.x); av[1] = (short)f2bf(p0.y);
        av[2] = (short)f2bf(p0.z); av[3] = (short)f2bf(p0.w);
        av[4] = (short)f2bf(p1.x); av[5] = (short)f2bf(p1.y);
        av[6] = (short)f2bf(p1.z); av[7] = (short)f2bf(p1.w);
      } else {
        av = (bf16x8)0;
      }
      *(bf16x8*)&As[row * 40 + kg] = av;
    }
#pragma unroll
    for (int p = 0; p < 5; ++p) {
      int idx = tid + p * 256;
      int n = idx >> 2, kg = (idx & 3) * 8;
      *(bf16x8*)&Bs[n * 40 + kg] = *(const bf16x8*)(w1t + (size_t)n * 256 + k0 + kg);
    }
    __syncthreads();
    bf16x8 af[4], bfr[5];
#pragma unroll
    for (int mt = 0; mt < 4; ++mt)
      af[mt] = *(const bf16x8*)&As[(mt * 16 + lr) * 40 + lq * 8];
#pragma unroll
    for (int nt = 0; nt < 5; ++nt) {
      int tile = nt * 4 + w;
      bfr[nt] = *(const bf16x8*)&Bs[(tile * 16 + lr) * 40 + lq * 8];
    }
#pragma unroll
    for (int mt = 0; mt < 4; ++mt)
#pragma unroll
      for (int nt = 0; nt < 5; ++nt)
        acc[mt][nt] = __builtin_amdgcn_mfma_f32_16x16x32_bf16(af[mt], bfr[nt], acc[mt][nt], 0, 0, 0);
    __syncthreads();
  }
#pragma unroll
  for (int mt = 0; mt < 4; ++mt)
#pragma unroll
    for (int nt = 0; nt < 5; ++nt) {
      int tile = nt * 4 + w;
      if (tile < 16) {
        int colc = tile * 16 + lr;
        int s = colc >> 5, c = colc & 31;
#pragma unroll
        for (int r = 0; r < 4; ++r) {
          int row = m0 + mt * 16 + lq * 4 + r;
          xw1s[((size_t)s * NPAD + row) * 32 + c] = f2bf(acc[mt][nt][r]);
        }
      } else if (tile == 16) {
#pragma unroll
        for (int r = 0; r < 4; ++r) {
          int row = m0 + mt * 16 + lq * 4 + r;
          if (lr < 8) a1sx[(size_t)lr * NPAD + row] = acc[mt][nt][r];
          else        a1dx[(size_t)(lr - 8) * NPAD + row] = acc[mt][nt][r];
        }
      }
    }
}

// ---------------- GEMM2: [xw2b | a2s | a2d] = hb @ w2t^T via MFMA, LDS-free -----------
__global__ __launch_bounds__(256) void gemm2_mfma(
    const ushort* __restrict__ hb, const ushort* __restrict__ w2t,
    ushort* __restrict__ xw2b, float* __restrict__ a2s, float* __restrict__ a2d) {
  const int tid = threadIdx.x;
  const int w = tid >> 6, l = tid & 63, lr = l & 15, lq = l >> 4;
  const int row0 = blockIdx.x * 64 + w * 16;
  f32x4 acc[3];
#pragma unroll
  for (int i = 0; i < 3; ++i) acc[i] = (f32x4)0.f;
#pragma unroll
  for (int ks = 0; ks < 8; ++ks) {
    int k0 = ks * 32;
    bf16x8 af = *(const bf16x8*)(hb + (size_t)(row0 + lr) * 256 + k0 + lq * 8);
#pragma unroll
    for (int nt = 0; nt < 3; ++nt) {
      bf16x8 bfr = *(const bf16x8*)(w2t + (size_t)(nt * 16 + lr) * 256 + k0 + lq * 8);
      acc[nt] = __builtin_amdgcn_mfma_f32_16x16x32_bf16(af, bfr, acc[nt], 0, 0, 0);
    }
  }
#pragma unroll
  for (int nt = 0; nt < 3; ++nt) {
    int colc = nt * 16 + lr;
#pragma unroll
    for (int r = 0; r < 4; ++r) {
      int row = row0 + lq * 4 + r;
      if (colc < NCLS)      xw2b[(size_t)row * 40 + colc] = f2bf(acc[nt][r]);
      else if (colc == 40)  a2s[row] = acc[nt][r];
      else if (colc == 41)  a2d[row] = acc[nt][r];
    }
  }
}

// ---------------- CSR build ----------------
__global__ __launch_bounds__(256) void hist_k(const int* __restrict__ dstA, int* __restrict__ cnt) {
  int e = blockIdx.x * 256 + threadIdx.x;
  if (e >= ETOT) return;
  int d = (e < NEDGES) ? dstA[e] : (e - NEDGES);
  atomicAdd(&cnt[d], 1);
}

__global__ __launch_bounds__(SCAN_B) void scan1_k(const int* __restrict__ deg,
                                                  int* __restrict__ row_ptr,
                                                  int* __restrict__ bsum) {
  __shared__ int sm[SCAN_B];
  int b = blockIdx.x, t = threadIdx.x;
  int idx = b * SCAN_B + t;
  int v = (idx < NNODES) ? deg[idx] : 0;
  sm[t] = v;
  __syncthreads();
#pragma unroll
  for (int off = 1; off < SCAN_B; off <<= 1) {
    int u = (t >= off) ? sm[t - off] : 0;
    __syncthreads();
    sm[t] += u;
    __syncthreads();
  }
  if (idx < NNODES) row_ptr[idx + 1] = sm[t];
  if (t == SCAN_B - 1) bsum[b] = sm[t];
}

// fused scan2+scan3
__global__ __launch_bounds__(SCAN_B) void scan23_k(const int* __restrict__ bsum,
                                                   int* __restrict__ row_ptr) {
  __shared__ int sm[SCAN_B];
  int b = blockIdx.x, t = threadIdx.x;
  sm[t] = (t < NSCB) ? bsum[t] : 0;
  __syncthreads();
#pragma unroll
  for (int off = 1; off < SCAN_B; off <<= 1) {
    int u = (t >= off) ? sm[t - off] : 0;
    __syncthreads();
    sm[t] += u;
    __syncthreads();
  }
  int offb = (b > 0) ? sm[b - 1] : 0;
  int idx = b * SCAN_B + t;
  if (idx < NNODES) row_ptr[idx + 1] += offb;
  if (b == 0 && t == 0) row_ptr[0] = 0;
}

// degree histogram via per-block LDS histogram (int LDS atomics are native/fast)
__global__ __launch_bounds__(256) void deghist_k(const int* __restrict__ row_ptr,
                                                 int* __restrict__ dbin) {
  __shared__ int lh[256];
  int t = threadIdx.x;
  lh[t] = 0;
  __syncthreads();
  int n = blockIdx.x * 256 + t;
  if (n < NNODES) {
    int deg = row_ptr[n + 1] - row_ptr[n];
    atomicAdd(&lh[(deg < 255) ? deg : 255], 1);
  }
  __syncthreads();
  if (lh[t] > 0) atomicAdd(&dbin[t], lh[t]);
}

// exclusive scan of 256 degree bins (in place)
__global__ __launch_bounds__(256) void binscan_k(int* __restrict__ dbin) {
  __shared__ int sm[256];
  int t = threadIdx.x;
  sm[t] = dbin[t];
  __syncthreads();
#pragma unroll
  for (int off = 1; off < 256; off <<= 1) {
    int u = (t >= off) ? sm[t - off] : 0;
    __syncthreads();
    sm[t] += u;
    __syncthreads();
  }
  dbin[t] = (t > 0) ? sm[t - 1] : 0;
}

// two-level counting-sort placement: LDS rank + one range-reservation atomic per (bin,block)
__global__ __launch_bounds__(256) void perm_k(const int* __restrict__ row_ptr,
                                              int* __restrict__ dbin,
                                              int* __restrict__ perm) {
  __shared__ int lcount[256];
  __shared__ int lbase[256];
  int t = threadIdx.x;
  lcount[t] = 0;
  __syncthreads();
  int n = blockIdx.x * 256 + t;
  int bin = 0, rank = 0;
  bool valid = (n < NNODES);
  if (valid) {
    int deg = row_ptr[n + 1] - row_ptr[n];
    bin = (deg < 255) ? deg : 255;
    rank = atomicAdd(&lcount[bin], 1);
  }
  __syncthreads();
  if (lcount[t] > 0) lbase[t] = atomicAdd(&dbin[t], lcount[t]);
  __syncthreads();
  if (valid) perm[lbase[bin] + rank] = n;
}

// scatter via atomicSub: cnt holds degrees on entry, zeros on exit
__global__ __launch_bounds__(256) void scatter_k(const int* __restrict__ srcA, const int* __restrict__ dstA,
                                                 const int* __restrict__ row_ptr, int* __restrict__ cnt,
                                                 int* __restrict__ col) {
  int e = blockIdx.x * 256 + threadIdx.x;
  if (e >= ETOT) return;
  int s, d;
  if (e < NEDGES) { s = srcA[e]; d = dstA[e]; }
  else { s = d = e - NEDGES; }
  int old = atomicSub(&cnt[d], 1);
  col[row_ptr[d] + old - 1] = s;
}

// ---------------- layer-1 aggregate: lane owns (node, 8ch), XCD-sliced, degree-sorted ---
__global__ __launch_bounds__(256) void agg1_k(
    const ushort* __restrict__ xw1s, const float* __restrict__ a1sx, const float* __restrict__ a1dx,
    const int* __restrict__ row_ptr, const int* __restrict__ col, const int* __restrict__ perm,
    const float* __restrict__ b1, ushort* __restrict__ hb) {
  const int b = blockIdx.x;
  const int s = b & 7;
  const int t = threadIdx.x;
  const int slot = (b >> 3) * 64 + (t >> 2);
  const int q = t & 3;                           // channel quad: 8 channels
  if (slot >= NNODES) return;
  const int node = perm[slot];
  const ushort* xs = xw1s + (size_t)s * NPAD * 32 + q * 8;
  const float* as = a1sx + (size_t)s * NPAD;
  const float ad = a1dx[(size_t)s * NPAD + node];
  int i = row_ptr[node];
  const int end = row_ptr[node + 1];
  float den = 0.f;
  float c0 = 0.f, c1 = 0.f, c2 = 0.f, c3 = 0.f, c4 = 0.f, c5 = 0.f, c6 = 0.f, c7 = 0.f;
  for (; i + 2 <= end; i += 2) {
    int s0 = col[i], s1 = col[i + 1];
    uint4 u0 = *(const uint4*)(xs + (size_t)s0 * 32);
    uint4 u1 = *(const uint4*)(xs + (size_t)s1 * 32);
    float e0 = as[s0] + ad;
    float e1 = as[s1] + ad;
    float w0 = __expf(fmaxf(e0, 0.f) + NEG * fminf(e0, 0.f));
    float w1 = __expf(fmaxf(e1, 0.f) + NEG * fminf(e1, 0.f));
    den += w0 + w1;
    c0 += w0 * bflo(u0.x) + w1 * bflo(u1.x);
    c1 += w0 * bfhi(u0.x) + w1 * bfhi(u1.x);
    c2 += w0 * bflo(u0.y) + w1 * bflo(u1.y);
    c3 += w0 * bfhi(u0.y) + w1 * bfhi(u1.y);
    c4 += w0 * bflo(u0.z) + w1 * bflo(u1.z);
    c5 += w0 * bfhi(u0.z) + w1 * bfhi(u1.z);
    c6 += w0 * bflo(u0.w) + w1 * bflo(u1.w);
    c7 += w0 * bfhi(u0.w) + w1 * bfhi(u1.w);
  }
  if (i < end) {
    int s0 = col[i];
    uint4 u0 = *(const uint4*)(xs + (size_t)s0 * 32);
    float e0 = as[s0] + ad;
    float w0 = __expf(fmaxf(e0, 0.f) + NEG * fminf(e0, 0.f));
    den += w0;
    c0 += w0 * bflo(u0.x); c1 += w0 * bfhi(u0.x);
    c2 += w0 * bflo(u0.y); c3 += w0 * bfhi(u0.y);
    c4 += w0 * bflo(u0.z); c5 += w0 * bfhi(u0.z);
    c6 += w0 * bflo(u0.w); c7 += w0 * bfhi(u0.w);
  }
  const float inv = 1.f / den;
  const float4 bv0 = *reinterpret_cast<const float4*>(b1 + s * 32 + q * 8);
  const float4 bv1 = *reinterpret_cast<const float4*>(b1 + s * 32 + q * 8 + 4);
  float o[8];
  o[0] = c0 * inv + bv0.x; o[1] = c1 * inv + bv0.y;
  o[2] = c2 * inv + bv0.z; o[3] = c3 * inv + bv0.w;
  o[4] = c4 * inv + bv1.x; o[5] = c5 * inv + bv1.y;
  o[6] = c6 * inv + bv1.z; o[7] = c7 * inv + bv1.w;
  uint4 pk;
  unsigned r[4];
#pragma unroll
  for (int p = 0; p < 4; ++p) {
    float a = o[2 * p],     va = (a > 0.f) ? a : expm1f(a);
    float c = o[2 * p + 1], vc = (c > 0.f) ? c : expm1f(c);
    r[p] = (unsigned)f2bf(va) | ((unsigned)f2bf(vc) << 16);
  }
  pk.x = r[0]; pk.y = r[1]; pk.z = r[2]; pk.w = r[3];
  *(uint4*)(hb + (size_t)node * 256 + s * 32 + q * 8) = pk;
}

// ---------------- layer-2 aggregate: 1 wave per node (bf16 gather, pitch 40) ----------
__global__ __launch_bounds__(256) void agg2_k(
    const ushort* __restrict__ xw2b, const float* __restrict__ a2s, const float* __restrict__ a2d,
    const int* __restrict__ row_ptr, const int* __restrict__ col,
    const float* __restrict__ b2, float* __restrict__ out, int n) {
  int wid = (blockIdx.x * 256 + threadIdx.x) >> 6;
  if (wid >= n) return;
  int lane = threadIdx.x & 63;
  int beg = row_ptr[wid], end = row_ptr[wid + 1];
  float ad = a2d[wid];
  float denom = 0.f, acc = 0.f;
  int i = beg;
  for (; i + 4 <= end; i += 4) {
    int s0 = col[i], s1 = col[i + 1], s2 = col[i + 2], s3 = col[i + 3];
    float e0 = a2s[s0] + ad;
    float e1 = a2s[s1] + ad;
    float e2 = a2s[s2] + ad;
    float e3 = a2s[s3] + ad;
    float w0 = __expf(fmaxf(e0, 0.f) + NEG * fminf(e0, 0.f));
    float w1 = __expf(fmaxf(e1, 0.f) + NEG * fminf(e1, 0.f));
    float w2 = __expf(fmaxf(e2, 0.f) + NEG * fminf(e2, 0.f));
    float w3 = __expf(fmaxf(e3, 0.f) + NEG * fminf(e3, 0.f));
    float x0 = 0.f, x1 = 0.f, x2 = 0.f, x3 = 0.f;
    if (lane < NCLS) {
      x0 = bf2f(xw2b[(size_t)s0 * 40 + lane]);
      x1 = bf2f(xw2b[(size_t)s1 * 40 + lane]);
      x2 = bf2f(xw2b[(size_t)s2 * 40 + lane]);
      x3 = bf2f(xw2b[(size_t)s3 * 40 + lane]);
    }
    denom += (w0 + w1) + (w2 + w3);
    acc += w0 * x0 + w1 * x1 + w2 * x2 + w3 * x3;
  }
  for (; i < end; ++i) {
    int s = col[i];
    float e = a2s[s] + ad;
    float w = __expf(fmaxf(e, 0.f) + NEG * fminf(e, 0.f));
    denom += w;
    if (lane < NCLS) acc += w * bf2f(xw2b[(size_t)s * 40 + lane]);
  }
  if (lane < NCLS) out[(size_t)wid * 40 + lane] = acc / denom + b2[lane];
}

extern "C" void kernel_launch(void* const* d_in, const int* in_sizes, int n_in,
                              void* d_out, int out_size, void* d_ws, size_t ws_size,
                              hipStream_t stream) {
  const float* x     = (const float*)d_in[0];
  const int*   ei    = (const int*)d_in[1];
  const float* W1    = (const float*)d_in[2];
  const float* a1src = (const float*)d_in[3];
  const float* a1dst = (const float*)d_in[4];
  const float* b1    = (const float*)d_in[5];
  const float* W2    = (const float*)d_in[6];
  const float* a2src = (const float*)d_in[7];
  const float* a2dst = (const float*)d_in[8];
  const float* b2    = (const float*)d_in[9];
  float* out = (float*)d_out;

  const int* srcA = ei;
  const int* dstA = ei + NEDGES;

  // workspace layout
  ushort* w1t  = (ushort*)d_ws;                     // [320][256]
  ushort* w2t  = w1t + (size_t)320 * 256;           // [64][256]
  ushort* xw1s = w2t + (size_t)64 * 256;            // [8][NPAD][32] slice-major
  ushort* hb   = xw1s + (size_t)NPAD * 256;         // [NPAD][256]
  ushort* xw2b = hb + (size_t)NPAD * 256;           // [NPAD][40]
  float* a1sx  = (float*)(xw2b + (size_t)NPAD * 40);// [8][NPAD]
  float* a1dx  = a1sx + (size_t)8 * NPAD;           // [8][NPAD]
  float* a2s   = a1dx + (size_t)8 * NPAD;           // NPAD
  float* a2d   = a2s + NPAD;                        // NPAD
  int* row_ptr = (int*)(a2d + NPAD);                // NNODES+1
  int* cnt     = row_ptr + (NNODES + 1);            // NNODES
  int* col     = cnt + NNODES;                      // ETOT
  int* bsum    = col + ETOT;                        // NSCB
  int* dbin    = bsum + NSCB;                       // 256
  int* perm    = dbin + 256;                        // NNODES

  prep_k<<<629, 256, 0, stream>>>(W1, W2, a1src, a1dst, a2src, a2dst, w1t, w2t, cnt, hb, dbin);

  gemm1_mfma<<<NPAD / 64, 256, 0, stream>>>(x, w1t, xw1s, a1sx, a1dx);

  hist_k<<<(ETOT + 255) / 256, 256, 0, stream>>>(dstA, cnt);
  scan1_k<<<NSCB, SCAN_B, 0, stream>>>(cnt, row_ptr, bsum);
  scan23_k<<<NSCB, SCAN_B, 0, stream>>>(bsum, row_ptr);
  deghist_k<<<NSCB, 256, 0, stream>>>(row_ptr, dbin);
  binscan_k<<<1, 256, 0, stream>>>(dbin);
  perm_k<<<NSCB, 256, 0, stream>>>(row_ptr, dbin, perm);
  scatter_k<<<(ETOT + 255) / 256, 256, 0, stream>>>(srcA, dstA, row_ptr, cnt, col);

  agg1_k<<<NTILE1 * 8, 256, 0, stream>>>(xw1s, a1sx, a1dx, row_ptr, col, perm, b1, hb);

  gemm2_mfma<<<NPAD / 64, 256, 0, stream>>>(hb, w2t, xw2b, a2s, a2d);

  agg2_k<<<(NNODES + 3) / 4, 256, 0, stream>>>(xw2b, a2s, a2d, row_ptr, col, b2, out, NNODES);
}

// Round 20
// 266.081 us; speedup vs baseline: 2.1430x; 1.0666x over previous
//
#include <hip/hip_runtime.h>
#include <hip/hip_bf16.h>

#define NNODES 50000
#define NPAD   50048
#define NEDGES 800000
#define ETOT   (NEDGES + NNODES)
#define FIN    256
#define HIDS   32
#define HEADS  8
#define NCLS   40
#define NEG    0.2f

#define SCAN_B 256
#define NSCB   ((NNODES + SCAN_B - 1) / SCAN_B)   // 196
#define NTILE1 ((NNODES + 63) / 64)               // 782 node-tiles

typedef __attribute__((ext_vector_type(8))) short bf16x8;
typedef __attribute__((ext_vector_type(4))) float f32x4;

__device__ __forceinline__ ushort f2bf(float f) {
  unsigned u = __float_as_uint(f);
  unsigned r = (u + 0x7fffu + ((u >> 16) & 1u)) >> 16;   // RNE
  return (ushort)r;
}
__device__ __forceinline__ float bf2f(ushort u) {
  return __uint_as_float(((unsigned)u) << 16);
}
__device__ __forceinline__ float bflo(unsigned u) { return __uint_as_float(u << 16); }
__device__ __forceinline__ float bfhi(unsigned u) { return __uint_as_float(u & 0xffff0000u); }

// ---------------- prep: w1t[320][256], w2t[64][256], cnt=0, hb pad rows=0 ----------------
__global__ __launch_bounds__(256) void prep_k(
    const float* __restrict__ W1, const float* __restrict__ W2,
    const float* __restrict__ a1src, const float* __restrict__ a1dst,
    const float* __restrict__ a2src, const float* __restrict__ a2dst,
    ushort* __restrict__ w1t, ushort* __restrict__ w2t,
    int* __restrict__ cnt, ushort* __restrict__ hb) {
  int b = blockIdx.x, t = threadIdx.x;
  if (b < 256) {
    int k = b, n = t;
    w1t[(size_t)n * 256 + k] = f2bf(W1[(size_t)k * 256 + n]);
  } else if (b < 272) {
    int j = b - 256, k = t;
    const float* av = (j < 8) ? (a1src + j * 32) : (a1dst + (j - 8) * 32);
    int nb = (j < 8) ? j * 32 : (j - 8) * 32;
    float s = 0.f;
#pragma unroll
    for (int c = 0; c < 32; ++c) s += W1[(size_t)k * 256 + nb + c] * av[c];
    w1t[(size_t)(256 + j) * 256 + k] = f2bf(s);
  } else if (b < 320) {
    w1t[(size_t)b * 256 + t] = 0;     // rows 272..319 zero
  } else if (b < 384) {
    int n = b - 320, k = t;
    ushort v;
    if (n < NCLS) {
      v = f2bf(W2[(size_t)k * NCLS + n]);
    } else if (n == 40) {
      float s = 0.f;
#pragma unroll
      for (int c = 0; c < NCLS; ++c) s += W2[(size_t)k * NCLS + c] * a2src[c];
      v = f2bf(s);
    } else if (n == 41) {
      float s = 0.f;
#pragma unroll
      for (int c = 0; c < NCLS; ++c) s += W2[(size_t)k * NCLS + c] * a2dst[c];
      v = f2bf(s);
    } else {
      v = 0;
    }
    w2t[(size_t)n * 256 + k] = v;
  } else if (b < 580) {
    int i = (b - 384) * 256 + t;
    if (i < NNODES) cnt[i] = 0;
  } else {
    int r = NNODES + (b - 580);
    hb[(size_t)r * 256 + t] = 0;
  }
}

// ---------------- GEMM1: [xw1s(slice-major) | a1sx | a1dx (slice-major)] via MFMA --------
__global__ __launch_bounds__(256) void gemm1_mfma(
    const float* __restrict__ x, const ushort* __restrict__ w1t,
    ushort* __restrict__ xw1s, float* __restrict__ a1sx, float* __restrict__ a1dx) {
  __shared__ ushort As[64 * 40];
  __shared__ ushort Bs[320 * 40];
  const int tid = threadIdx.x;
  const int m0 = blockIdx.x * 64;
  const int w = tid >> 6, l = tid & 63, lr = l & 15, lq = l >> 4;
  f32x4 acc[4][5];
#pragma unroll
  for (int i = 0; i < 4; ++i)
#pragma unroll
    for (int j = 0; j < 5; ++j) acc[i][j] = (f32x4)0.f;

  for (int k0 = 0; k0 < 256; k0 += 32) {
    {
      int row = tid >> 2, kg = (tid & 3) * 8;
      int gr = m0 + row;
      bf16x8 av;
      if (gr < NNODES) {
        const float4* xp = (const float4*)(x + (size_t)gr * 256 + k0 + kg);
        float4 p0 = xp[0], p1 = xp[1];
        av[0] = (short)f2bf(p0.x); av[1] = (short)f2bf(p0.y);
        av[2] = (short)f2bf(p0.z); av[3] = (short)f2bf(p0.w);
        av[4] = (short)f2bf(p1.x); av[5] = (short)f2bf(p1.y);
        av[6] = (short)f2bf(p1.z); av[7] = (short)f2bf(p1.w);
      } else {
        av = (bf16x8)0;
      }
      *(bf16x8*)&As[row * 40 + kg] = av;
    }
#pragma unroll
    for (int p = 0; p < 5; ++p) {
      int idx = tid + p * 256;
      int n = idx >> 2, kg = (idx & 3) * 8;
      *(bf16x8*)&Bs[n * 40 + kg] = *(const bf16x8*)(w1t + (size_t)n * 256 + k0 + kg);
    }
    __syncthreads();
    bf16x8 af[4], bfr[5];
#pragma unroll
    for (int mt = 0; mt < 4; ++mt)
      af[mt] = *(const bf16x8*)&As[(mt * 16 + lr) * 40 + lq * 8];
#pragma unroll
    for (int nt = 0; nt < 5; ++nt) {
      int tile = nt * 4 + w;
      bfr[nt] = *(const bf16x8*)&Bs[(tile * 16 + lr) * 40 + lq * 8];
    }
#pragma unroll
    for (int mt = 0; mt < 4; ++mt)
#pragma unroll
      for (int nt = 0; nt < 5; ++nt)
        acc[mt][nt] = __builtin_amdgcn_mfma_f32_16x16x32_bf16(af[mt], bfr[nt], acc[mt][nt], 0, 0, 0);
    __syncthreads();
  }
#pragma unroll
  for (int mt = 0; mt < 4; ++mt)
#pragma unroll
    for (int nt = 0; nt < 5; ++nt) {
      int tile = nt * 4 + w;
      if (tile < 16) {
        int colc = tile * 16 + lr;
        int s = colc >> 5, c = colc & 31;
#pragma unroll
        for (int r = 0; r < 4; ++r) {
          int row = m0 + mt * 16 + lq * 4 + r;
          xw1s[((size_t)s * NPAD + row) * 32 + c] = f2bf(acc[mt][nt][r]);
        }
      } else if (tile == 16) {
#pragma unroll
        for (int r = 0; r < 4; ++r) {
          int row = m0 + mt * 16 + lq * 4 + r;
          if (lr < 8) a1sx[(size_t)lr * NPAD + row] = acc[mt][nt][r];
          else        a1dx[(size_t)(lr - 8) * NPAD + row] = acc[mt][nt][r];
        }
      }
    }
}

// ---------------- GEMM2: [xw2b | a2s | a2d] = hb @ w2t^T via MFMA, LDS-free -----------
__global__ __launch_bounds__(256) void gemm2_mfma(
    const ushort* __restrict__ hb, const ushort* __restrict__ w2t,
    ushort* __restrict__ xw2b, float* __restrict__ a2s, float* __restrict__ a2d) {
  const int tid = threadIdx.x;
  const int w = tid >> 6, l = tid & 63, lr = l & 15, lq = l >> 4;
  const int row0 = blockIdx.x * 64 + w * 16;
  f32x4 acc[3];
#pragma unroll
  for (int i = 0; i < 3; ++i) acc[i] = (f32x4)0.f;
#pragma unroll
  for (int ks = 0; ks < 8; ++ks) {
    int k0 = ks * 32;
    bf16x8 af = *(const bf16x8*)(hb + (size_t)(row0 + lr) * 256 + k0 + lq * 8);
#pragma unroll
    for (int nt = 0; nt < 3; ++nt) {
      bf16x8 bfr = *(const bf16x8*)(w2t + (size_t)(nt * 16 + lr) * 256 + k0 + lq * 8);
      acc[nt] = __builtin_amdgcn_mfma_f32_16x16x32_bf16(af, bfr, acc[nt], 0, 0, 0);
    }
  }
#pragma unroll
  for (int nt = 0; nt < 3; ++nt) {
    int colc = nt * 16 + lr;
#pragma unroll
    for (int r = 0; r < 4; ++r) {
      int row = row0 + lq * 4 + r;
      if (colc < NCLS)      xw2b[(size_t)row * 40 + colc] = f2bf(acc[nt][r]);
      else if (colc == 40)  a2s[row] = acc[nt][r];
      else if (colc == 41)  a2d[row] = acc[nt][r];
    }
  }
}

// ---------------- CSR build ----------------
__global__ __launch_bounds__(256) void hist_k(const int* __restrict__ dstA, int* __restrict__ cnt) {
  int e = blockIdx.x * 256 + threadIdx.x;
  if (e >= ETOT) return;
  int d = (e < NEDGES) ? dstA[e] : (e - NEDGES);
  atomicAdd(&cnt[d], 1);
}

__global__ __launch_bounds__(SCAN_B) void scan1_k(const int* __restrict__ deg,
                                                  int* __restrict__ row_ptr,
                                                  int* __restrict__ bsum) {
  __shared__ int sm[SCAN_B];
  int b = blockIdx.x, t = threadIdx.x;
  int idx = b * SCAN_B + t;
  int v = (idx < NNODES) ? deg[idx] : 0;
  sm[t] = v;
  __syncthreads();
#pragma unroll
  for (int off = 1; off < SCAN_B; off <<= 1) {
    int u = (t >= off) ? sm[t - off] : 0;
    __syncthreads();
    sm[t] += u;
    __syncthreads();
  }
  if (idx < NNODES) row_ptr[idx + 1] = sm[t];
  if (t == SCAN_B - 1) bsum[b] = sm[t];
}

// fused scan2+scan3
__global__ __launch_bounds__(SCAN_B) void scan23_k(const int* __restrict__ bsum,
                                                   int* __restrict__ row_ptr) {
  __shared__ int sm[SCAN_B];
  int b = blockIdx.x, t = threadIdx.x;
  sm[t] = (t < NSCB) ? bsum[t] : 0;
  __syncthreads();
#pragma unroll
  for (int off = 1; off < 256; off <<= 1) {
    int u = (t >= off) ? sm[t - off] : 0;
    __syncthreads();
    sm[t] += u;
    __syncthreads();
  }
  int offb = (b > 0) ? sm[b - 1] : 0;
  int idx = b * SCAN_B + t;
  if (idx < NNODES) row_ptr[idx + 1] += offb;
  if (b == 0 && t == 0) row_ptr[0] = 0;
}

// scatter via atomicSub: cnt holds degrees on entry, zeros on exit
__global__ __launch_bounds__(256) void scatter_k(const int* __restrict__ srcA, const int* __restrict__ dstA,
                                                 const int* __restrict__ row_ptr, int* __restrict__ cnt,
                                                 int* __restrict__ col) {
  int e = blockIdx.x * 256 + threadIdx.x;
  if (e >= ETOT) return;
  int s, d;
  if (e < NEDGES) { s = srcA[e]; d = dstA[e]; }
  else { s = d = e - NEDGES; }
  int old = atomicSub(&cnt[d], 1);
  col[row_ptr[d] + old - 1] = s;
}

// ---------------- layer-1 aggregate: lane owns (node, 8ch), XCD-sliced ----------------
// block = (slice s = blockIdx&7 -> XCD, 64-node tile = blockIdx>>3).
// Per-tile degree rank-sort in LDS: wave w handles degree-ranked slots [16w,16w+16)
// of ITS OWN tile -> minimal intra-wave loop divergence, col locality preserved.
__global__ __launch_bounds__(256) void agg1_k(
    const ushort* __restrict__ xw1s, const float* __restrict__ a1sx, const float* __restrict__ a1dx,
    const int* __restrict__ row_ptr, const int* __restrict__ col,
    const float* __restrict__ b1, ushort* __restrict__ hb) {
  __shared__ int sdeg[64];
  __shared__ int snode[64];
  const int b = blockIdx.x;
  const int s = b & 7;
  const int n0 = (b >> 3) * 64;
  const int t = threadIdx.x;
  if (t < 64) {
    int nn = n0 + t;
    sdeg[t] = (nn < NNODES) ? (row_ptr[nn + 1] - row_ptr[nn]) : -1;
  }
  __syncthreads();
  if (t < 64) {
    int d = sdeg[t];
    int rank = 0;
#pragma unroll 8
    for (int j = 0; j < 64; ++j) {
      int dj = sdeg[j];
      rank += (dj < d) || (dj == d && j < t);
    }
    snode[rank] = n0 + t;    // ascending degree; invalid (-1) nodes land first
  }
  __syncthreads();
  const int slot = t >> 2;
  const int node = snode[slot];
  const int q = t & 3;                           // channel quad: 8 channels
  if (node >= NNODES) return;
  const ushort* xs = xw1s + (size_t)s * NPAD * 32 + q * 8;
  const float* as = a1sx + (size_t)s * NPAD;
  const float ad = a1dx[(size_t)s * NPAD + node];
  int i = row_ptr[node];
  const int end = row_ptr[node + 1];
  float den = 0.f;
  float c0 = 0.f, c1 = 0.f, c2 = 0.f, c3 = 0.f, c4 = 0.f, c5 = 0.f, c6 = 0.f, c7 = 0.f;
  for (; i + 2 <= end; i += 2) {
    int s0 = col[i], s1 = col[i + 1];
    uint4 u0 = *(const uint4*)(xs + (size_t)s0 * 32);
    uint4 u1 = *(const uint4*)(xs + (size_t)s1 * 32);
    float e0 = as[s0] + ad;
    float e1 = as[s1] + ad;
    float w0 = __expf(fmaxf(e0, 0.f) + NEG * fminf(e0, 0.f));
    float w1 = __expf(fmaxf(e1, 0.f) + NEG * fminf(e1, 0.f));
    den += w0 + w1;
    c0 += w0 * bflo(u0.x) + w1 * bflo(u1.x);
    c1 += w0 * bfhi(u0.x) + w1 * bfhi(u1.x);
    c2 += w0 * bflo(u0.y) + w1 * bflo(u1.y);
    c3 += w0 * bfhi(u0.y) + w1 * bfhi(u1.y);
    c4 += w0 * bflo(u0.z) + w1 * bflo(u1.z);
    c5 += w0 * bfhi(u0.z) + w1 * bfhi(u1.z);
    c6 += w0 * bflo(u0.w) + w1 * bflo(u1.w);
    c7 += w0 * bfhi(u0.w) + w1 * bfhi(u1.w);
  }
  if (i < end) {
    int s0 = col[i];
    uint4 u0 = *(const uint4*)(xs + (size_t)s0 * 32);
    float e0 = as[s0] + ad;
    float w0 = __expf(fmaxf(e0, 0.f) + NEG * fminf(e0, 0.f));
    den += w0;
    c0 += w0 * bflo(u0.x); c1 += w0 * bfhi(u0.x);
    c2 += w0 * bflo(u0.y); c3 += w0 * bfhi(u0.y);
    c4 += w0 * bflo(u0.z); c5 += w0 * bfhi(u0.z);
    c6 += w0 * bflo(u0.w); c7 += w0 * bfhi(u0.w);
  }
  const float inv = 1.f / den;
  const float4 bv0 = *reinterpret_cast<const float4*>(b1 + s * 32 + q * 8);
  const float4 bv1 = *reinterpret_cast<const float4*>(b1 + s * 32 + q * 8 + 4);
  float o[8];
  o[0] = c0 * inv + bv0.x; o[1] = c1 * inv + bv0.y;
  o[2] = c2 * inv + bv0.z; o[3] = c3 * inv + bv0.w;
  o[4] = c4 * inv + bv1.x; o[5] = c5 * inv + bv1.y;
  o[6] = c6 * inv + bv1.z; o[7] = c7 * inv + bv1.w;
  uint4 pk;
  unsigned r[4];
#pragma unroll
  for (int p = 0; p < 4; ++p) {
    float a = o[2 * p],     va = (a > 0.f) ? a : expm1f(a);
    float c = o[2 * p + 1], vc = (c > 0.f) ? c : expm1f(c);
    r[p] = (unsigned)f2bf(va) | ((unsigned)f2bf(vc) << 16);
  }
  pk.x = r[0]; pk.y = r[1]; pk.z = r[2]; pk.w = r[3];
  *(uint4*)(hb + (size_t)node * 256 + s * 32 + q * 8) = pk;
}

// ---------------- layer-2 aggregate: 1 wave per node (bf16 gather, pitch 40) ----------
__global__ __launch_bounds__(256) void agg2_k(
    const ushort* __restrict__ xw2b, const float* __restrict__ a2s, const float* __restrict__ a2d,
    const int* __restrict__ row_ptr, const int* __restrict__ col,
    const float* __restrict__ b2, float* __restrict__ out, int n) {
  int wid = (blockIdx.x * 256 + threadIdx.x) >> 6;
  if (wid >= n) return;
  int lane = threadIdx.x & 63;
  int beg = row_ptr[wid], end = row_ptr[wid + 1];
  float ad = a2d[wid];
  float denom = 0.f, acc = 0.f;
  int i = beg;
  for (; i + 4 <= end; i += 4) {
    int s0 = col[i], s1 = col[i + 1], s2 = col[i + 2], s3 = col[i + 3];
    float e0 = a2s[s0] + ad;
    float e1 = a2s[s1] + ad;
    float e2 = a2s[s2] + ad;
    float e3 = a2s[s3] + ad;
    float w0 = __expf(fmaxf(e0, 0.f) + NEG * fminf(e0, 0.f));
    float w1 = __expf(fmaxf(e1, 0.f) + NEG * fminf(e1, 0.f));
    float w2 = __expf(fmaxf(e2, 0.f) + NEG * fminf(e2, 0.f));
    float w3 = __expf(fmaxf(e3, 0.f) + NEG * fminf(e3, 0.f));
    float x0 = 0.f, x1 = 0.f, x2 = 0.f, x3 = 0.f;
    if (lane < NCLS) {
      x0 = bf2f(xw2b[(size_t)s0 * 40 + lane]);
      x1 = bf2f(xw2b[(size_t)s1 * 40 + lane]);
      x2 = bf2f(xw2b[(size_t)s2 * 40 + lane]);
      x3 = bf2f(xw2b[(size_t)s3 * 40 + lane]);
    }
    denom += (w0 + w1) + (w2 + w3);
    acc += w0 * x0 + w1 * x1 + w2 * x2 + w3 * x3;
  }
  for (; i < end; ++i) {
    int s = col[i];
    float e = a2s[s] + ad;
    float w = __expf(fmaxf(e, 0.f) + NEG * fminf(e, 0.f));
    denom += w;
    if (lane < NCLS) acc += w * bf2f(xw2b[(size_t)s * 40 + lane]);
  }
  if (lane < NCLS) out[(size_t)wid * 40 + lane] = acc / denom + b2[lane];
}

extern "C" void kernel_launch(void* const* d_in, const int* in_sizes, int n_in,
                              void* d_out, int out_size, void* d_ws, size_t ws_size,
                              hipStream_t stream) {
  const float* x     = (const float*)d_in[0];
  const int*   ei    = (const int*)d_in[1];
  const float* W1    = (const float*)d_in[2];
  const float* a1src = (const float*)d_in[3];
  const float* a1dst = (const float*)d_in[4];
  const float* b1    = (const float*)d_in[5];
  const float* W2    = (const float*)d_in[6];
  const float* a2src = (const float*)d_in[7];
  const float* a2dst = (const float*)d_in[8];
  const float* b2    = (const float*)d_in[9];
  float* out = (float*)d_out;

  const int* srcA = ei;
  const int* dstA = ei + NEDGES;

  // workspace layout
  ushort* w1t  = (ushort*)d_ws;                     // [320][256]
  ushort* w2t  = w1t + (size_t)320 * 256;           // [64][256]
  ushort* xw1s = w2t + (size_t)64 * 256;            // [8][NPAD][32] slice-major
  ushort* hb   = xw1s + (size_t)NPAD * 256;         // [NPAD][256]
  ushort* xw2b = hb + (size_t)NPAD * 256;           // [NPAD][40]
  float* a1sx  = (float*)(xw2b + (size_t)NPAD * 40);// [8][NPAD]
  float* a1dx  = a1sx + (size_t)8 * NPAD;           // [8][NPAD]
  float* a2s   = a1dx + (size_t)8 * NPAD;           // NPAD
  float* a2d   = a2s + NPAD;                        // NPAD
  int* row_ptr = (int*)(a2d + NPAD);                // NNODES+1
  int* cnt     = row_ptr + (NNODES + 1);            // NNODES
  int* col     = cnt + NNODES;                      // ETOT
  int* bsum    = col + ETOT;                        // NSCB

  prep_k<<<628, 256, 0, stream>>>(W1, W2, a1src, a1dst, a2src, a2dst, w1t, w2t, cnt, hb);

  gemm1_mfma<<<NPAD / 64, 256, 0, stream>>>(x, w1t, xw1s, a1sx, a1dx);

  hist_k<<<(ETOT + 255) / 256, 256, 0, stream>>>(dstA, cnt);
  scan1_k<<<NSCB, SCAN_B, 0, stream>>>(cnt, row_ptr, bsum);
  scan23_k<<<NSCB, SCAN_B, 0, stream>>>(bsum, row_ptr);
  scatter_k<<<(ETOT + 255) / 256, 256, 0, stream>>>(srcA, dstA, row_ptr, cnt, col);

  agg1_k<<<NTILE1 * 8, 256, 0, stream>>>(xw1s, a1sx, a1dx, row_ptr, col, b1, hb);

  gemm2_mfma<<<NPAD / 64, 256, 0, stream>>>(hb, w2t, xw2b, a2s, a2d);

  agg2_k<<<(NNODES + 3) / 4, 256, 0, stream>>>(xw2b, a2s, a2d, row_ptr, col, b2, out, NNODES);
}

// Round 21
// 252.609 us; speedup vs baseline: 2.2573x; 1.0533x over previous
//
#include <hip/hip_runtime.h>
#include <hip/hip_bf16.h>

#define NNODES 50000
#define NPAD   50048
#define NEDGES 800000
#define ETOT   (NEDGES + NNODES)
#define FIN    256
#define HIDS   32
#define HEADS  8
#define NCLS   40
#define NEG    0.2f

#define SCAN_B 256
#define NSCB   ((NNODES + SCAN_B - 1) / SCAN_B)   // 196
#define NTILE1 ((NNODES + 63) / 64)               // 782 node-tiles
#define NGEMM1 (NPAD / 64)                        // 782
#define NHISTB ((ETOT + 255) / 256)               // 3322

typedef __attribute__((ext_vector_type(8))) short bf16x8;
typedef __attribute__((ext_vector_type(4))) float f32x4;

__device__ __forceinline__ ushort f2bf(float f) {
  unsigned u = __float_as_uint(f);
  unsigned r = (u + 0x7fffu + ((u >> 16) & 1u)) >> 16;   // RNE
  return (ushort)r;
}
__device__ __forceinline__ float bf2f(ushort u) {
  return __uint_as_float(((unsigned)u) << 16);
}
__device__ __forceinline__ float bflo(unsigned u) { return __uint_as_float(u << 16); }
__device__ __forceinline__ float bfhi(unsigned u) { return __uint_as_float(u & 0xffff0000u); }

// ---------------- prep: w1t[320][256], w2t[64][256], cnt=0, hb pad rows=0 ----------------
__global__ __launch_bounds__(256) void prep_k(
    const float* __restrict__ W1, const float* __restrict__ W2,
    const float* __restrict__ a1src, const float* __restrict__ a1dst,
    const float* __restrict__ a2src, const float* __restrict__ a2dst,
    ushort* __restrict__ w1t, ushort* __restrict__ w2t,
    int* __restrict__ cnt, ushort* __restrict__ hb) {
  int b = blockIdx.x, t = threadIdx.x;
  if (b < 256) {
    int k = b, n = t;
    w1t[(size_t)n * 256 + k] = f2bf(W1[(size_t)k * 256 + n]);
  } else if (b < 272) {
    int j = b - 256, k = t;
    const float* av = (j < 8) ? (a1src + j * 32) : (a1dst + (j - 8) * 32);
    int nb = (j < 8) ? j * 32 : (j - 8) * 32;
    float s = 0.f;
#pragma unroll
    for (int c = 0; c < 32; ++c) s += W1[(size_t)k * 256 + nb + c] * av[c];
    w1t[(size_t)(256 + j) * 256 + k] = f2bf(s);
  } else if (b < 320) {
    w1t[(size_t)b * 256 + t] = 0;     // rows 272..319 zero
  } else if (b < 384) {
    int n = b - 320, k = t;
    ushort v;
    if (n < NCLS) {
      v = f2bf(W2[(size_t)k * NCLS + n]);
    } else if (n == 40) {
      float s = 0.f;
#pragma unroll
      for (int c = 0; c < NCLS; ++c) s += W2[(size_t)k * NCLS + c] * a2src[c];
      v = f2bf(s);
    } else if (n == 41) {
      float s = 0.f;
#pragma unroll
      for (int c = 0; c < NCLS; ++c) s += W2[(size_t)k * NCLS + c] * a2dst[c];
      v = f2bf(s);
    } else {
      v = 0;
    }
    w2t[(size_t)n * 256 + k] = v;
  } else if (b < 580) {
    int i = (b - 384) * 256 + t;
    if (i < NNODES) cnt[i] = 0;
  } else {
    int r = NNODES + (b - 580);
    hb[(size_t)r * 256 + t] = 0;
  }
}

// ---------------- fused GEMM1 + degree histogram ----------------
// blocks [0, NGEMM1): MFMA gemm -> xw1s (slice-major) + a1sx/a1dx (slice-major)
// blocks [NGEMM1, NGEMM1+NHISTB): degree histogram (runs on idle CU slots)
__global__ __launch_bounds__(256) void gemm1_hist_k(
    const float* __restrict__ x, const ushort* __restrict__ w1t,
    ushort* __restrict__ xw1s, float* __restrict__ a1sx, float* __restrict__ a1dx,
    const int* __restrict__ dstA, int* __restrict__ cnt) {
  __shared__ ushort As[64 * 40];
  __shared__ ushort Bs[320 * 40];
  const int blk = blockIdx.x;
  const int tid = threadIdx.x;
  if (blk >= NGEMM1) {
    int e = (blk - NGEMM1) * 256 + tid;
    if (e < ETOT) {
      int d = (e < NEDGES) ? dstA[e] : (e - NEDGES);
      atomicAdd(&cnt[d], 1);
    }
    return;
  }
  const int m0 = blk * 64;
  const int w = tid >> 6, l = tid & 63, lr = l & 15, lq = l >> 4;
  f32x4 acc[4][5];
#pragma unroll
  for (int i = 0; i < 4; ++i)
#pragma unroll
    for (int j = 0; j < 5; ++j) acc[i][j] = (f32x4)0.f;

  for (int k0 = 0; k0 < 256; k0 += 32) {
    {
      int row = tid >> 2, kg = (tid & 3) * 8;
      int gr = m0 + row;
      bf16x8 av;
      if (gr < NNODES) {
        const float4* xp = (const float4*)(x + (size_t)gr * 256 + k0 + kg);
        float4 p0 = xp[0], p1 = xp[1];
        av[0] = (short)f2bf(p0.x); av[1] = (short)f2bf(p0.y);
        av[2] = (short)f2bf(p0.z); av[3] = (short)f2bf(p0.w);
        av[4] = (short)f2bf(p1.x); av[5] = (short)f2bf(p1.y);
        av[6] = (short)f2bf(p1.z); av[7] = (short)f2bf(p1.w);
      } else {
        av = (bf16x8)0;
      }
      *(bf16x8*)&As[row * 40 + kg] = av;
    }
#pragma unroll
    for (int p = 0; p < 5; ++p) {
      int idx = tid + p * 256;
      int n = idx >> 2, kg = (idx & 3) * 8;
      *(bf16x8*)&Bs[n * 40 + kg] = *(const bf16x8*)(w1t + (size_t)n * 256 + k0 + kg);
    }
    __syncthreads();
    bf16x8 af[4], bfr[5];
#pragma unroll
    for (int mt = 0; mt < 4; ++mt)
      af[mt] = *(const bf16x8*)&As[(mt * 16 + lr) * 40 + lq * 8];
#pragma unroll
    for (int nt = 0; nt < 5; ++nt) {
      int tile = nt * 4 + w;
      bfr[nt] = *(const bf16x8*)&Bs[(tile * 16 + lr) * 40 + lq * 8];
    }
#pragma unroll
    for (int mt = 0; mt < 4; ++mt)
#pragma unroll
      for (int nt = 0; nt < 5; ++nt)
        acc[mt][nt] = __builtin_amdgcn_mfma_f32_16x16x32_bf16(af[mt], bfr[nt], acc[mt][nt], 0, 0, 0);
    __syncthreads();
  }
#pragma unroll
  for (int mt = 0; mt < 4; ++mt)
#pragma unroll
    for (int nt = 0; nt < 5; ++nt) {
      int tile = nt * 4 + w;
      if (tile < 16) {
        int colc = tile * 16 + lr;
        int s = colc >> 5, c = colc & 31;
#pragma unroll
        for (int r = 0; r < 4; ++r) {
          int row = m0 + mt * 16 + lq * 4 + r;
          xw1s[((size_t)s * NPAD + row) * 32 + c] = f2bf(acc[mt][nt][r]);
        }
      } else if (tile == 16) {
#pragma unroll
        for (int r = 0; r < 4; ++r) {
          int row = m0 + mt * 16 + lq * 4 + r;
          if (lr < 8) a1sx[(size_t)lr * NPAD + row] = acc[mt][nt][r];
          else        a1dx[(size_t)(lr - 8) * NPAD + row] = acc[mt][nt][r];
        }
      }
    }
}

// ---------------- GEMM2: [xw2b | a2s | a2d] = hb @ w2t^T via MFMA, LDS-free -----------
__global__ __launch_bounds__(256) void gemm2_mfma(
    const ushort* __restrict__ hb, const ushort* __restrict__ w2t,
    ushort* __restrict__ xw2b, float* __restrict__ a2s, float* __restrict__ a2d) {
  const int tid = threadIdx.x;
  const int w = tid >> 6, l = tid & 63, lr = l & 15, lq = l >> 4;
  const int row0 = blockIdx.x * 64 + w * 16;
  f32x4 acc[3];
#pragma unroll
  for (int i = 0; i < 3; ++i) acc[i] = (f32x4)0.f;
#pragma unroll
  for (int ks = 0; ks < 8; ++ks) {
    int k0 = ks * 32;
    bf16x8 af = *(const bf16x8*)(hb + (size_t)(row0 + lr) * 256 + k0 + lq * 8);
#pragma unroll
    for (int nt = 0; nt < 3; ++nt) {
      bf16x8 bfr = *(const bf16x8*)(w2t + (size_t)(nt * 16 + lr) * 256 + k0 + lq * 8);
      acc[nt] = __builtin_amdgcn_mfma_f32_16x16x32_bf16(af, bfr, acc[nt], 0, 0, 0);
    }
  }
#pragma unroll
  for (int nt = 0; nt < 3; ++nt) {
    int colc = nt * 16 + lr;
#pragma unroll
    for (int r = 0; r < 4; ++r) {
      int row = row0 + lq * 4 + r;
      if (colc < NCLS)      xw2b[(size_t)row * 40 + colc] = f2bf(acc[nt][r]);
      else if (colc == 40)  a2s[row] = acc[nt][r];
      else if (colc == 41)  a2d[row] = acc[nt][r];
    }
  }
}

// ---------------- CSR scan ----------------
__global__ __launch_bounds__(SCAN_B) void scan1_k(const int* __restrict__ deg,
                                                  int* __restrict__ row_ptr,
                                                  int* __restrict__ bsum) {
  __shared__ int sm[SCAN_B];
  int b = blockIdx.x, t = threadIdx.x;
  int idx = b * SCAN_B + t;
  int v = (idx < NNODES) ? deg[idx] : 0;
  sm[t] = v;
  __syncthreads();
#pragma unroll
  for (int off = 1; off < SCAN_B; off <<= 1) {
    int u = (t >= off) ? sm[t - off] : 0;
    __syncthreads();
    sm[t] += u;
    __syncthreads();
  }
  if (idx < NNODES) row_ptr[idx + 1] = sm[t];
  if (t == SCAN_B - 1) bsum[b] = sm[t];
}

// fused scan2+scan3
__global__ __launch_bounds__(SCAN_B) void scan23_k(const int* __restrict__ bsum,
                                                   int* __restrict__ row_ptr) {
  __shared__ int sm[SCAN_B];
  int b = blockIdx.x, t = threadIdx.x;
  sm[t] = (t < NSCB) ? bsum[t] : 0;
  __syncthreads();
#pragma unroll
  for (int off = 1; off < SCAN_B; off <<= 1) {
    int u = (t >= off) ? sm[t - off] : 0;
    __syncthreads();
    sm[t] += u;
    __syncthreads();
  }
  int offb = (b > 0) ? sm[b - 1] : 0;
  int idx = b * SCAN_B + t;
  if (idx < NNODES) row_ptr[idx + 1] += offb;
  if (b == 0 && t == 0) row_ptr[0] = 0;
}

// scatter via atomicSub: cnt holds degrees on entry, zeros on exit
__global__ __launch_bounds__(256) void scatter_k(const int* __restrict__ srcA, const int* __restrict__ dstA,
                                                 const int* __restrict__ row_ptr, int* __restrict__ cnt,
                                                 int* __restrict__ col) {
  int e = blockIdx.x * 256 + threadIdx.x;
  if (e >= ETOT) return;
  int s, d;
  if (e < NEDGES) { s = srcA[e]; d = dstA[e]; }
  else { s = d = e - NEDGES; }
  int old = atomicSub(&cnt[d], 1);
  col[row_ptr[d] + old - 1] = s;
}

// ---------------- layer-1 aggregate: lane owns (node, 8ch), XCD-sliced ----------------
__global__ __launch_bounds__(256) void agg1_k(
    const ushort* __restrict__ xw1s, const float* __restrict__ a1sx, const float* __restrict__ a1dx,
    const int* __restrict__ row_ptr, const int* __restrict__ col,
    const float* __restrict__ b1, ushort* __restrict__ hb) {
  const int b = blockIdx.x;
  const int s = b & 7;
  const int t = threadIdx.x;
  const int node = (b >> 3) * 64 + (t >> 2);
  const int q = t & 3;                           // channel quad: 8 channels
  if (node >= NNODES) return;
  const ushort* xs = xw1s + (size_t)s * NPAD * 32 + q * 8;
  const float* as = a1sx + (size_t)s * NPAD;
  const float ad = a1dx[(size_t)s * NPAD + node];
  int i = row_ptr[node];
  const int end = row_ptr[node + 1];
  float den = 0.f;
  float c0 = 0.f, c1 = 0.f, c2 = 0.f, c3 = 0.f, c4 = 0.f, c5 = 0.f, c6 = 0.f, c7 = 0.f;
  for (; i + 2 <= end; i += 2) {
    int s0 = col[i], s1 = col[i + 1];
    uint4 u0 = *(const uint4*)(xs + (size_t)s0 * 32);
    uint4 u1 = *(const uint4*)(xs + (size_t)s1 * 32);
    float e0 = as[s0] + ad;
    float e1 = as[s1] + ad;
    float w0 = __expf(fmaxf(e0, 0.f) + NEG * fminf(e0, 0.f));
    float w1 = __expf(fmaxf(e1, 0.f) + NEG * fminf(e1, 0.f));
    den += w0 + w1;
    c0 += w0 * bflo(u0.x) + w1 * bflo(u1.x);
    c1 += w0 * bfhi(u0.x) + w1 * bfhi(u1.x);
    c2 += w0 * bflo(u0.y) + w1 * bflo(u1.y);
    c3 += w0 * bfhi(u0.y) + w1 * bfhi(u1.y);
    c4 += w0 * bflo(u0.z) + w1 * bflo(u1.z);
    c5 += w0 * bfhi(u0.z) + w1 * bfhi(u1.z);
    c6 += w0 * bflo(u0.w) + w1 * bflo(u1.w);
    c7 += w0 * bfhi(u0.w) + w1 * bfhi(u1.w);
  }
  if (i < end) {
    int s0 = col[i];
    uint4 u0 = *(const uint4*)(xs + (size_t)s0 * 32);
    float e0 = as[s0] + ad;
    float w0 = __expf(fmaxf(e0, 0.f) + NEG * fminf(e0, 0.f));
    den += w0;
    c0 += w0 * bflo(u0.x); c1 += w0 * bfhi(u0.x);
    c2 += w0 * bflo(u0.y); c3 += w0 * bfhi(u0.y);
    c4 += w0 * bflo(u0.z); c5 += w0 * bfhi(u0.z);
    c6 += w0 * bflo(u0.w); c7 += w0 * bfhi(u0.w);
  }
  const float inv = 1.f / den;
  const float4 bv0 = *reinterpret_cast<const float4*>(b1 + s * 32 + q * 8);
  const float4 bv1 = *reinterpret_cast<const float4*>(b1 + s * 32 + q * 8 + 4);
  float o[8];
  o[0] = c0 * inv + bv0.x; o[1] = c1 * inv + bv0.y;
  o[2] = c2 * inv + bv0.z; o[3] = c3 * inv + bv0.w;
  o[4] = c4 * inv + bv1.x; o[5] = c5 * inv + bv1.y;
  o[6] = c6 * inv + bv1.z; o[7] = c7 * inv + bv1.w;
  uint4 pk;
  unsigned r[4];
#pragma unroll
  for (int p = 0; p < 4; ++p) {
    float a = o[2 * p],     va = (a > 0.f) ? a : expm1f(a);
    float c = o[2 * p + 1], vc = (c > 0.f) ? c : expm1f(c);
    r[p] = (unsigned)f2bf(va) | ((unsigned)f2bf(vc) << 16);
  }
  pk.x = r[0]; pk.y = r[1]; pk.z = r[2]; pk.w = r[3];
  *(uint4*)(hb + (size_t)node * 256 + s * 32 + q * 8) = pk;
}

// ---------------- layer-2 aggregate: 1 wave per node (bf16 gather, pitch 40) ----------
__global__ __launch_bounds__(256) void agg2_k(
    const ushort* __restrict__ xw2b, const float* __restrict__ a2s, const float* __restrict__ a2d,
    const int* __restrict__ row_ptr, const int* __restrict__ col,
    const float* __restrict__ b2, float* __restrict__ out, int n) {
  int wid = (blockIdx.x * 256 + threadIdx.x) >> 6;
  if (wid >= n) return;
  int lane = threadIdx.x & 63;
  int beg = row_ptr[wid], end = row_ptr[wid + 1];
  float ad = a2d[wid];
  float denom = 0.f, acc = 0.f;
  int i = beg;
  for (; i + 4 <= end; i += 4) {
    int s0 = col[i], s1 = col[i + 1], s2 = col[i + 2], s3 = col[i + 3];
    float e0 = a2s[s0] + ad;
    float e1 = a2s[s1] + ad;
    float e2 = a2s[s2] + ad;
    float e3 = a2s[s3] + ad;
    float w0 = __expf(fmaxf(e0, 0.f) + NEG * fminf(e0, 0.f));
    float w1 = __expf(fmaxf(e1, 0.f) + NEG * fminf(e1, 0.f));
    float w2 = __expf(fmaxf(e2, 0.f) + NEG * fminf(e2, 0.f));
    float w3 = __expf(fmaxf(e3, 0.f) + NEG * fminf(e3, 0.f));
    float x0 = 0.f, x1 = 0.f, x2 = 0.f, x3 = 0.f;
    if (lane < NCLS) {
      x0 = bf2f(xw2b[(size_t)s0 * 40 + lane]);
      x1 = bf2f(xw2b[(size_t)s1 * 40 + lane]);
      x2 = bf2f(xw2b[(size_t)s2 * 40 + lane]);
      x3 = bf2f(xw2b[(size_t)s3 * 40 + lane]);
    }
    denom += (w0 + w1) + (w2 + w3);
    acc += w0 * x0 + w1 * x1 + w2 * x2 + w3 * x3;
  }
  for (; i < end; ++i) {
    int s = col[i];
    float e = a2s[s] + ad;
    float w = __expf(fmaxf(e, 0.f) + NEG * fminf(e, 0.f));
    denom += w;
    if (lane < NCLS) acc += w * bf2f(xw2b[(size_t)s * 40 + lane]);
  }
  if (lane < NCLS) out[(size_t)wid * 40 + lane] = acc / denom + b2[lane];
}

extern "C" void kernel_launch(void* const* d_in, const int* in_sizes, int n_in,
                              void* d_out, int out_size, void* d_ws, size_t ws_size,
                              hipStream_t stream) {
  const float* x     = (const float*)d_in[0];
  const int*   ei    = (const int*)d_in[1];
  const float* W1    = (const float*)d_in[2];
  const float* a1src = (const float*)d_in[3];
  const float* a1dst = (const float*)d_in[4];
  const float* b1    = (const float*)d_in[5];
  const float* W2    = (const float*)d_in[6];
  const float* a2src = (const float*)d_in[7];
  const float* a2dst = (const float*)d_in[8];
  const float* b2    = (const float*)d_in[9];
  float* out = (float*)d_out;

  const int* srcA = ei;
  const int* dstA = ei + NEDGES;

  // workspace layout
  ushort* w1t  = (ushort*)d_ws;                     // [320][256]
  ushort* w2t  = w1t + (size_t)320 * 256;           // [64][256]
  ushort* xw1s = w2t + (size_t)64 * 256;            // [8][NPAD][32] slice-major
  ushort* hb   = xw1s + (size_t)NPAD * 256;         // [NPAD][256]
  ushort* xw2b = hb + (size_t)NPAD * 256;           // [NPAD][40]
  float* a1sx  = (float*)(xw2b + (size_t)NPAD * 40);// [8][NPAD]
  float* a1dx  = a1sx + (size_t)8 * NPAD;           // [8][NPAD]
  float* a2s   = a1dx + (size_t)8 * NPAD;           // NPAD
  float* a2d   = a2s + NPAD;                        // NPAD
  int* row_ptr = (int*)(a2d + NPAD);                // NNODES+1
  int* cnt     = row_ptr + (NNODES + 1);            // NNODES
  int* col     = cnt + NNODES;                      // ETOT
  int* bsum    = col + ETOT;                        // NSCB

  prep_k<<<628, 256, 0, stream>>>(W1, W2, a1src, a1dst, a2src, a2dst, w1t, w2t, cnt, hb);

  gemm1_hist_k<<<NGEMM1 + NHISTB, 256, 0, stream>>>(x, w1t, xw1s, a1sx, a1dx, dstA, cnt);

  scan1_k<<<NSCB, SCAN_B, 0, stream>>>(cnt, row_ptr, bsum);
  scan23_k<<<NSCB, SCAN_B, 0, stream>>>(bsum, row_ptr);
  scatter_k<<<(ETOT + 255) / 256, 256, 0, stream>>>(srcA, dstA, row_ptr, cnt, col);

  agg1_k<<<NTILE1 * 8, 256, 0, stream>>>(xw1s, a1sx, a1dx, row_ptr, col, b1, hb);

  gemm2_mfma<<<NPAD / 64, 256, 0, stream>>>(hb, w2t, xw2b, a2s, a2d);

  agg2_k<<<(NNODES + 3) / 4, 256, 0, stream>>>(xw2b, a2s, a2d, row_ptr, col, b2, out, NNODES);
}